// Round 4
// baseline (600.202 us; speedup 1.0000x reference)
//
#include <hip/hip_runtime.h>
#include <stdint.h>

// MPLayer: edge MLP (7->96->160->192, lrelu all) over 128x75x75 pairs, sum over j,
// node MLP (195->256->256->3, lrelu first two). bf16 MFMA compute, fp32 accum.
// R4: edge W3 moved out of LDS into fragment-contiguous global layout (1KB
// coalesced uint4 wave-reads from L2); LDS 126->63KB => 2 blocks/CU; panel
// packing via v_cvt_pk_bf16_f32.
// ws: agg fp32 [9600][192] (7,372,800 B) then bf16 weights (360,576 B).

#define ALPHA 0.2f
#define EDGE_ROWS 720000
#define ROWS_PER_BLOCK 256
#define EDGE_BLOCKS 2813  // ceil(720000/256)

typedef __attribute__((ext_vector_type(8))) short short8v;
typedef __attribute__((ext_vector_type(16))) float float16v;
typedef __attribute__((ext_vector_type(4))) float float4v;

__device__ __forceinline__ uint16_t f2bf(float f) {
  uint32_t u = __builtin_bit_cast(uint32_t, f);
  u += 0x7FFFu + ((u >> 16) & 1u);   // round-to-nearest-even
  return (uint16_t)(u >> 16);
}
__device__ __forceinline__ float bf2f(uint16_t h) {
  uint32_t u = ((uint32_t)h) << 16;
  return __builtin_bit_cast(float, u);
}
// leaky relu, 2 VALU ops (valid for 0<ALPHA<1)
__device__ __forceinline__ float lrelu(float v) { return fmaxf(v, ALPHA * v); }
__device__ __forceinline__ float16v zero16() {
  float16v z;
#pragma unroll
  for (int i = 0; i < 16; ++i) z[i] = 0.f;
  return z;
}
__device__ __forceinline__ float4v zero4() {
  float4v z;
#pragma unroll
  for (int i = 0; i < 4; ++i) z[i] = 0.f;
  return z;
}
// 8 consecutive bf16 as two 8B loads (8B-aligned)
__device__ __forceinline__ short8v load8(const uint16_t* p) {
  union { uint2 u2[2]; short8v v; } t;
  t.u2[0] = *(const uint2*)(p);
  t.u2[1] = *(const uint2*)(p + 4);
  return t.v;
}
__device__ __forceinline__ short8v frag32(const uint16_t* base, int stride, int r0,
                                          int k0, int lane) {
  int row = r0 + (lane & 31);
  return load8(base + row * stride + k0 + ((lane >> 5) << 3));
}
// pack 2 f32 -> 2 bf16 (RNE) in one instruction; lo=a, hi=b
__device__ __forceinline__ uint32_t pk2(float a, float b) {
  uint32_t r;
  asm("v_cvt_pk_bf16_f32 %0, %1, %2" : "=v"(r) : "v"(a), "v"(b));
  return r;
}

// ---------------- prep: weights -> bf16, bias folded into K ----------------
#define S0 (96*20)       // w1T  [96][20]   k<7 = W, k==7 = bias, else 0
#define S1 (160*116)     // w2T  [160][116] k<96 = W, k==96 = bias, else 0
#define S2 (6*10*2*32*8) // w3G  fragment-contiguous: [(n3*10+kt)*2+h][lm][e]
#define S3 (256*228)     // fnw1T[256][228] k<195
#define S4 (256*260)     // fnw2T[256][260] k<256
#define S5 (16*260)      // fnw3T[16][260]  n<3,k<256
#define PREP_TOTAL (S0+S1+S2+S3+S4+S5)  // 180288

__global__ void prep_kernel(const float* __restrict__ few1, const float* __restrict__ feb1,
                            const float* __restrict__ few2, const float* __restrict__ feb2,
                            const float* __restrict__ few3,
                            const float* __restrict__ fnw1, const float* __restrict__ fnw2,
                            const float* __restrict__ fnw3,
                            uint16_t* __restrict__ wsb) {
  int idx = blockIdx.x * 256 + threadIdx.x;
  if (idx >= PREP_TOTAL) return;
  float v = 0.f;
  int j = idx;
  if (j < S0) {
    int n = j / 20, k = j % 20;
    if (k < 7) v = few1[k * 96 + n];
    else if (k == 7) v = feb1[n];
  } else if ((j -= S0) < S1) {
    int n = j / 116, k = j % 116;
    if (k < 96) v = few2[k * 160 + n];
    else if (k == 96) v = feb2[n];
  } else if ((j -= S1) < S2) {
    // w3G: frag=(n3*10+kt)*2+h, lane, e ; n=n3*32+lane, k=kt*16+h*8+e (<160 always)
    int frag = j >> 8, lane = (j >> 3) & 31, e = j & 7;
    int n3 = frag / 20, rem = frag % 20, kt = rem >> 1, hh = rem & 1;
    v = few3[(kt * 16 + hh * 8 + e) * 192 + n3 * 32 + lane];
  } else if ((j -= S2) < S3) {
    int n = j / 228, k = j % 228;
    if (k < 195) v = fnw1[k * 256 + n];
  } else if ((j -= S3) < S4) {
    int n = j / 260, k = j % 260;
    if (k < 256) v = fnw2[k * 256 + n];
  } else {
    j -= S4;
    int n = j / 260, k = j % 260;
    if (n < 3 && k < 256) v = fnw3[k * 3 + n];
  }
  wsb[idx] = f2bf(v);
}

// ---------------- edge MLP + aggregation (fused, barrier-free body) ------------
// 2813 blocks x 512 thr; each wave owns 32 consecutive global rows (b,i,j).
// Swapped MFMA (A=weights, B=activations) for L1/L2 -> lane-local rows -> b64
// panel writes. L3 non-swapped with W3 streamed from L2 (coalesced 1KB frags).
__global__ __launch_bounds__(512, 4)
void edge_kernel(const float* __restrict__ x,
                 const float* __restrict__ feb3,
                 const uint16_t* __restrict__ w1T, const uint16_t* __restrict__ w2T,
                 const uint16_t* __restrict__ w3G, float* __restrict__ agg) {
  __shared__ __align__(16) uint16_t sW1[96 * 20];     //  3840 B
  __shared__ __align__(16) uint16_t sW2[160 * 116];   // 37120 B
  __shared__ __align__(16) uint16_t sPan[8][32 * 36]; // 18432 B wave-private panels
  __shared__ float sAgg[5 * 192];                     //  3840 B  => 63232 B total

  const int t = threadIdx.x, w = t >> 6, l = t & 63, h = l >> 5, lm = l & 31;
  const int R0 = blockIdx.x * ROWS_PER_BLOCK;

  {  // stage W1+W2 (uint4), zero sAgg
    const uint4* s1 = (const uint4*)w1T; uint4* d1 = (uint4*)sW1;
    for (int u = t; u < (96 * 20 * 2) / 16; u += 512) d1[u] = s1[u];
    const uint4* s2 = (const uint4*)w2T; uint4* d2 = (uint4*)sW2;
    for (int u = t; u < (160 * 116 * 2) / 16; u += 512) d2[u] = s2[u];
    for (int u = t; u < 960; u += 512) sAgg[u] = 0.f;
  }
  __syncthreads();

  const int rowg = R0 + w * 32;       // wave's first global row
  const int myrow = rowg + lm;
  uint16_t* pan = &sPan[w][0];

  // A0 fragment in registers: k0..6 = [xi, xj, dist], k7 = 1.0 (bias slot),
  // k8..15 = 0 (h==1 lanes all-zero; w1T zeros there too).
  short8v a0 = {0, 0, 0, 0, 0, 0, 0, 0};
  if (h == 0 && myrow < EDGE_ROWS) {
    int b = myrow / 5625, rb = myrow % 5625;
    int i = rb / 75, jj = rb % 75;
    const float* xb = x + b * 225;
    float xi0 = xb[i * 3], xi1 = xb[i * 3 + 1], xi2 = xb[i * 3 + 2];
    float xj0 = xb[jj * 3], xj1 = xb[jj * 3 + 1], xj2 = xb[jj * 3 + 2];
    float d0 = xj0 - xi0 + 1e-12f, d1 = xj1 - xi1 + 1e-12f, d2 = xj2 - xi2 + 1e-12f;
    float dist = sqrtf(d0 * d0 + d1 * d1 + d2 * d2);
    a0[0] = (short)f2bf(xi0); a0[1] = (short)f2bf(xi1); a0[2] = (short)f2bf(xi2);
    a0[3] = (short)f2bf(xj0); a0[4] = (short)f2bf(xj1); a0[5] = (short)f2bf(xj2);
    a0[6] = (short)f2bf(dist); a0[7] = (short)0x3F80;  // 1.0
  }

  // ---- L1 (panel) -> L2 accumulate; bias folded (L1 k=7, L2 k=96) ----
  float16v acc2[5];
#pragma unroll
  for (int n2 = 0; n2 < 5; ++n2) acc2[n2] = zero16();

#pragma unroll
  for (int nt1 = 0; nt1 < 3; ++nt1) {
    short8v wf = load8(sW1 + (nt1 * 32 + lm) * 20 + h * 8);
    float16v a = __builtin_amdgcn_mfma_f32_32x32x16_bf16(wf, a0, zero16(), 0, 0, 0);
    // pack H1 panel: lane holds row lm, n-quads {8q + 4h + 0..3}
#pragma unroll
    for (int q = 0; q < 4; ++q) {
      uint2 pv;
      pv.x = pk2(lrelu(a[q * 4 + 0]), lrelu(a[q * 4 + 1]));
      pv.y = pk2(lrelu(a[q * 4 + 2]), lrelu(a[q * 4 + 3]));
      *(uint2*)(pan + lm * 36 + q * 8 + h * 4) = pv;
    }
    // consume panel: 2 K-steps of L2 across all 5 n-tiles
#pragma unroll
    for (int kl = 0; kl < 2; ++kl) {
      int kt = nt1 * 2 + kl;
      short8v hf = load8(pan + lm * 36 + kl * 16 + h * 8);
#pragma unroll
      for (int n2 = 0; n2 < 5; ++n2) {
        short8v w2f = load8(sW2 + (n2 * 32 + lm) * 116 + kt * 16 + h * 8);
        acc2[n2] = __builtin_amdgcn_mfma_f32_32x32x16_bf16(w2f, hf, acc2[n2], 0, 0, 0);
      }
    }
  }
  {  // L2 bias K-step (k=96..111): B = const (1.0 at k=96 for h==0)
    short8v hc = {0, 0, 0, 0, 0, 0, 0, 0};
    if (h == 0) hc[0] = (short)0x3F80;
#pragma unroll
    for (int n2 = 0; n2 < 5; ++n2) {
      short8v w2f = load8(sW2 + (n2 * 32 + lm) * 116 + 96 + h * 8);
      acc2[n2] = __builtin_amdgcn_mfma_f32_32x32x16_bf16(w2f, hc, acc2[n2], 0, 0, 0);
    }
  }

  // ---- L2 finalize (panel) -> L3 accumulate (non-swapped, W3 from L2) ----
  float16v acc3[6];
#pragma unroll
  for (int n3 = 0; n3 < 6; ++n3) acc3[n3] = zero16();

  const uint4* w3f4 = (const uint4*)w3G;
#pragma unroll
  for (int n2 = 0; n2 < 5; ++n2) {
#pragma unroll
    for (int q = 0; q < 4; ++q) {
      uint2 pv;
      pv.x = pk2(lrelu(acc2[n2][q * 4 + 0]), lrelu(acc2[n2][q * 4 + 1]));
      pv.y = pk2(lrelu(acc2[n2][q * 4 + 2]), lrelu(acc2[n2][q * 4 + 3]));
      *(uint2*)(pan + lm * 36 + q * 8 + h * 4) = pv;
    }
#pragma unroll
    for (int kl = 0; kl < 2; ++kl) {
      short8v af = load8(pan + lm * 36 + kl * 16 + h * 8);  // A = H2 rows
#pragma unroll
      for (int n3 = 0; n3 < 6; ++n3) {
        union { uint4 u; short8v v; } wv;
        wv.u = w3f4[(n3 * 10 + n2 * 2 + kl) * 64 + l];  // coalesced 1KB fragment
        acc3[n3] = __builtin_amdgcn_mfma_f32_32x32x16_bf16(af, wv.v, acc3[n3], 0, 0, 0);
      }
    }
  }

  // ---- L3 finalize: bias + lrelu + masked j-sum into <=2 (b,i) groups ----
  {
    const int g0 = rowg / 75;
    const int gl0 = g0 - R0 / 75;            // 0..4
    const int s = 75 - rowg % 75;            // moff < s -> group g0
    const int vlim = min(32, EDGE_ROWS - rowg);
#pragma unroll
    for (int n3 = 0; n3 < 6; ++n3) {
      int col = n3 * 32 + lm;
      float bias = feb3[col];
      float p0 = 0.f, p1 = 0.f;
#pragma unroll
      for (int r = 0; r < 16; ++r) {
        int moff = (r & 3) + ((r >> 2) << 3) + (h << 2);
        float v = lrelu(acc3[n3][r] + bias);
        float vv = (moff < vlim) ? v : 0.f;
        if (moff < s) p0 += vv; else p1 += vv;
      }
      if (vlim > 0) {
        atomicAdd(&sAgg[gl0 * 192 + col], p0);
        if (s < 32) atomicAdd(&sAgg[(gl0 + 1) * 192 + col], p1);
      }
    }
  }

  __syncthreads();
  {  // flush block-local group sums to global (boundary groups shared -> atomic)
    const int gbase = R0 / 75;
    for (int u = t; u < 960; u += 512) {
      int g = gbase + u / 192;
      float v = sAgg[u];
      if (g < 9600 && v != 0.f) atomicAdd(&agg[g * 192 + (u % 192)], v);
    }
  }
}

// ---------------- node MLP (unchanged) ----------------
__global__ __launch_bounds__(512, 1)
void node_kernel(const float* __restrict__ x, const float* __restrict__ agg,
                 const float* __restrict__ fnb1, const float* __restrict__ fnb2,
                 const float* __restrict__ fnb3,
                 const uint16_t* __restrict__ fw1T, const uint16_t* __restrict__ fw2T,
                 const uint16_t* __restrict__ fw3T, float* __restrict__ out) {
  __shared__ __align__(16) uint16_t sY[64 * 228];
  __shared__ __align__(16) uint16_t sH1[64 * 260];
  __shared__ __align__(16) uint16_t sH2[64 * 260];
  __shared__ __align__(16) uint16_t sW[128 * 228];

  const int t = threadIdx.x;
  const int w = t >> 6, l = t & 63;
  const int n0 = blockIdx.x * 64;

  for (int u = t; u < 64 * 228; u += 512) {  // y hi/lo split
    int m = u / 228, c = u % 228;
    float v;
    if (c < 192) v = agg[(n0 + m) * 192 + c];
    else if (c < 195) v = x[(n0 + m) * 3 + (c - 192)];
    else v = 0.f;
    uint16_t hh = f2bf(v);
    sY[u] = hh;
    sH2[m * 260 + c] = f2bf(v - bf2f(hh));
  }
  __syncthreads();

  for (int p = 0; p < 2; ++p) {  // L1: hi+lo double MFMA
    const uint4* s = (const uint4*)(fw1T + p * 128 * 228);
    uint4* d = (uint4*)sW;
    for (int u = t; u < (128 * 228 * 2) / 16; u += 512) d[u] = s[u];
    __syncthreads();
    {
      int mt = w & 1, ntl = w >> 1;
      float16v acc = zero16();
      for (int kt = 0; kt < 14; ++kt) {
        short8v bb = frag32(sW, 228, ntl * 32, kt * 16, l);
        short8v ah = frag32(sY, 228, mt * 32, kt * 16, l);
        acc = __builtin_amdgcn_mfma_f32_32x32x16_bf16(ah, bb, acc, 0, 0, 0);
        short8v al = frag32(sH2, 260, mt * 32, kt * 16, l);
        acc = __builtin_amdgcn_mfma_f32_32x32x16_bf16(al, bb, acc, 0, 0, 0);
      }
      int col = (p * 4 + ntl) * 32 + (l & 31);
      float bias = fnb1[col];
#pragma unroll
      for (int r = 0; r < 16; ++r) {
        int row = (r & 3) + ((r >> 2) << 3) + ((l >> 5) << 2);
        sH1[(mt * 32 + row) * 260 + col] = f2bf(lrelu(acc[r] + bias));
      }
    }
    __syncthreads();
  }
  for (int q = 0; q < 4; ++q) {  // L2
    const uint4* s = (const uint4*)(fw2T + q * 64 * 260);
    uint4* d = (uint4*)sW;
    for (int u = t; u < (64 * 260 * 2) / 16; u += 512) d[u] = s[u];
    __syncthreads();
    if (w < 4) {
      int mt = w & 1, ntl = w >> 1;
      float16v acc = zero16();
      for (int kt = 0; kt < 16; ++kt) {
        short8v a = frag32(sH1, 260, mt * 32, kt * 16, l);
        short8v bb = frag32(sW, 260, ntl * 32, kt * 16, l);
        acc = __builtin_amdgcn_mfma_f32_32x32x16_bf16(a, bb, acc, 0, 0, 0);
      }
      int col = (q * 2 + ntl) * 32 + (l & 31);
      float bias = fnb2[col];
#pragma unroll
      for (int r = 0; r < 16; ++r) {
        int row = (r & 3) + ((r >> 2) << 3) + ((l >> 5) << 2);
        sH2[(mt * 32 + row) * 260 + col] = f2bf(lrelu(acc[r] + bias));
      }
    }
    __syncthreads();
  }
  if (w < 4) {  // L3: 256->3 linear, 16x16x32
    int mt = w;
    float4v acc = zero4();
    for (int kt = 0; kt < 8; ++kt) {
      short8v a = load8(sH2 + (mt * 16 + (l & 15)) * 260 + kt * 32 + ((l >> 4) << 3));
      short8v bb = load8(fw3T + (l & 15) * 260 + kt * 32 + ((l >> 4) << 3));
      acc = __builtin_amdgcn_mfma_f32_16x16x32_bf16(a, bb, acc, 0, 0, 0);
    }
    int col = l & 15;
    if (col < 3) {
      float bias = fnb3[col];
#pragma unroll
      for (int r = 0; r < 4; ++r) {
        int row = ((l >> 4) << 2) + r;
        out[(n0 + mt * 16 + row) * 3 + col] = acc[r] + bias;
      }
    }
  }
}

extern "C" void kernel_launch(void* const* d_in, const int* in_sizes, int n_in,
                              void* d_out, int out_size, void* d_ws, size_t ws_size,
                              hipStream_t stream) {
  (void)in_sizes; (void)n_in; (void)out_size; (void)ws_size;
  const float* x    = (const float*)d_in[0];
  const float* few1 = (const float*)d_in[1];
  const float* feb1 = (const float*)d_in[2];
  const float* few2 = (const float*)d_in[3];
  const float* feb2 = (const float*)d_in[4];
  const float* few3 = (const float*)d_in[5];
  const float* feb3 = (const float*)d_in[6];
  const float* fnw1 = (const float*)d_in[7];
  const float* fnb1 = (const float*)d_in[8];
  const float* fnw2 = (const float*)d_in[9];
  const float* fnb2 = (const float*)d_in[10];
  const float* fnw3 = (const float*)d_in[11];
  const float* fnb3 = (const float*)d_in[12];
  float* out = (float*)d_out;

  float* agg = (float*)d_ws;
  uint16_t* wsb = (uint16_t*)((char*)d_ws + 9600 * 192 * 4);
  const uint16_t* w1T  = wsb;
  const uint16_t* w2T  = wsb + S0;
  const uint16_t* w3G  = wsb + S0 + S1;
  const uint16_t* fw1T = wsb + S0 + S1 + S2;
  const uint16_t* fw2T = wsb + S0 + S1 + S2 + S3;
  const uint16_t* fw3T = wsb + S0 + S1 + S2 + S3 + S4;

  hipMemsetAsync(agg, 0, 9600 * 192 * sizeof(float), stream);  // atomic accum target
  prep_kernel<<<(PREP_TOTAL + 255) / 256, 256, 0, stream>>>(
      few1, feb1, few2, feb2, few3, fnw1, fnw2, fnw3, wsb);
  edge_kernel<<<EDGE_BLOCKS, 512, 0, stream>>>(x, feb3, w1T, w2T, w3G, agg);
  node_kernel<<<150, 512, 0, stream>>>(x, agg, fnb1, fnb2, fnb3, fw1T, fw2T, fw3T, out);
}

// Round 5
// 253.230 us; speedup vs baseline: 2.3702x; 2.3702x over previous
//
#include <hip/hip_runtime.h>
#include <stdint.h>

// MPLayer: edge MLP (7->96->160->192, lrelu all) over 128x75x75 pairs, sum over j,
// node MLP (195->256->256->3, lrelu first two). bf16 MFMA compute, fp32 accum.
// R5: edge panel LDS bounce replaced by in-register v_permlane32_swap_b32 repack
// (2 swaps per fragment); LDS 44.8KB => 3 blocks/CU; W3 streamed from L2 in
// fragment-contiguous layout; NO launch-bounds reg squeeze (R4 spilled).
// ws: agg fp32 [9600][192] (7,372,800 B) then bf16 weights (360,576 B).

#define ALPHA 0.2f
#define EDGE_ROWS 720000
#define ROWS_PER_BLOCK 256
#define EDGE_BLOCKS 2813  // ceil(720000/256)

typedef __attribute__((ext_vector_type(8))) short short8v;
typedef __attribute__((ext_vector_type(16))) float float16v;
typedef __attribute__((ext_vector_type(4))) float float4v;

__device__ __forceinline__ uint16_t f2bf(float f) {
  uint32_t u = __builtin_bit_cast(uint32_t, f);
  u += 0x7FFFu + ((u >> 16) & 1u);   // round-to-nearest-even
  return (uint16_t)(u >> 16);
}
__device__ __forceinline__ float bf2f(uint16_t h) {
  uint32_t u = ((uint32_t)h) << 16;
  return __builtin_bit_cast(float, u);
}
// leaky relu, 2 VALU ops (valid for 0<ALPHA<1)
__device__ __forceinline__ float lrelu(float v) { return fmaxf(v, ALPHA * v); }
__device__ __forceinline__ float16v zero16() {
  float16v z;
#pragma unroll
  for (int i = 0; i < 16; ++i) z[i] = 0.f;
  return z;
}
__device__ __forceinline__ float4v zero4() {
  float4v z;
#pragma unroll
  for (int i = 0; i < 4; ++i) z[i] = 0.f;
  return z;
}
// 8 consecutive bf16 as two 8B loads (8B-aligned)
__device__ __forceinline__ short8v load8(const uint16_t* p) {
  union { uint2 u2[2]; short8v v; } t;
  t.u2[0] = *(const uint2*)(p);
  t.u2[1] = *(const uint2*)(p + 4);
  return t.v;
}
__device__ __forceinline__ short8v frag32(const uint16_t* base, int stride, int r0,
                                          int k0, int lane) {
  int row = r0 + (lane & 31);
  return load8(base + row * stride + k0 + ((lane >> 5) << 3));
}
// pack 2 f32 -> 2 bf16 (RNE) in one instruction; lo=a, hi=b
__device__ __forceinline__ uint32_t pk2(float a, float b) {
  uint32_t r;
  asm("v_cvt_pk_bf16_f32 %0, %1, %2" : "=v"(r) : "v"(a), "v"(b));
  return r;
}
// swap: a[32..63] <-> b[0..31]  (v_permlane32_swap_b32, gfx950)
__device__ __forceinline__ void plswap(uint32_t& a, uint32_t& b) {
  asm volatile("v_permlane32_swap_b32 %0, %1" : "+v"(a), "+v"(b));
}
__device__ __forceinline__ short8v mk8(uint32_t w0, uint32_t w1, uint32_t w2,
                                       uint32_t w3) {
  union { uint32_t u[4]; short8v v; } t;
  t.u[0] = w0; t.u[1] = w1; t.u[2] = w2; t.u[3] = w3;
  return t.v;
}

// ---------------- prep: weights -> bf16, bias folded into K ----------------
#define S0 (96*20)       // w1T  [96][20]   k<7 = W, k==7 = bias, else 0
#define S1 (160*116)     // w2T  [160][116] k<96 = W, k==96 = bias, else 0
#define S2 (6*10*2*32*8) // w3G  fragment-contiguous: [(n3*10+kt)*2+h][lm][e]
#define S3 (256*228)     // fnw1T[256][228] k<195
#define S4 (256*260)     // fnw2T[256][260] k<256
#define S5 (16*260)      // fnw3T[16][260]  n<3,k<256
#define PREP_TOTAL (S0+S1+S2+S3+S4+S5)  // 180288

__global__ void prep_kernel(const float* __restrict__ few1, const float* __restrict__ feb1,
                            const float* __restrict__ few2, const float* __restrict__ feb2,
                            const float* __restrict__ few3,
                            const float* __restrict__ fnw1, const float* __restrict__ fnw2,
                            const float* __restrict__ fnw3,
                            uint16_t* __restrict__ wsb) {
  int idx = blockIdx.x * 256 + threadIdx.x;
  if (idx >= PREP_TOTAL) return;
  float v = 0.f;
  int j = idx;
  if (j < S0) {
    int n = j / 20, k = j % 20;
    if (k < 7) v = few1[k * 96 + n];
    else if (k == 7) v = feb1[n];
  } else if ((j -= S0) < S1) {
    int n = j / 116, k = j % 116;
    if (k < 96) v = few2[k * 160 + n];
    else if (k == 96) v = feb2[n];
  } else if ((j -= S1) < S2) {
    // w3G: frag=(n3*10+kt)*2+h, lane, e ; n=n3*32+lane, k=kt*16+h*8+e (<160 always)
    int frag = j >> 8, lane = (j >> 3) & 31, e = j & 7;
    int n3 = frag / 20, rem = frag % 20, kt = rem >> 1, hh = rem & 1;
    v = few3[(kt * 16 + hh * 8 + e) * 192 + n3 * 32 + lane];
  } else if ((j -= S2) < S3) {
    int n = j / 228, k = j % 228;
    if (k < 195) v = fnw1[k * 256 + n];
  } else if ((j -= S3) < S4) {
    int n = j / 260, k = j % 260;
    if (k < 256) v = fnw2[k * 256 + n];
  } else {
    j -= S4;
    int n = j / 260, k = j % 260;
    if (n < 3 && k < 256) v = fnw3[k * 3 + n];
  }
  wsb[idx] = f2bf(v);
}

// ---------------- edge MLP + aggregation (fused, barrier-free body) ------------
// 2813 blocks x 512 thr; each wave owns 32 consecutive global rows (b,i,j).
// Swapped MFMA (A=weights, B=activations) for L1/L2 -> each lane holds its own
// activation row's outputs -> next-layer fragments assembled with 2
// v_permlane32_swap_b32 per fragment (no LDS round trip). L3 non-swapped with
// W3 streamed from L2 (coalesced 1KB frags).
__global__ __launch_bounds__(512, 2)
void edge_kernel(const float* __restrict__ x,
                 const float* __restrict__ feb3,
                 const uint16_t* __restrict__ w1T, const uint16_t* __restrict__ w2T,
                 const uint16_t* __restrict__ w3G, float* __restrict__ agg) {
  __shared__ __align__(16) uint16_t sW1[96 * 20];     //  3840 B
  __shared__ __align__(16) uint16_t sW2[160 * 116];   // 37120 B
  __shared__ float sAgg[5 * 192];                     //  3840 B  => 44800 B total

  const int t = threadIdx.x, w = t >> 6, l = t & 63, h = l >> 5, lm = l & 31;
  const int R0 = blockIdx.x * ROWS_PER_BLOCK;

  {  // stage W1+W2 (uint4), zero sAgg
    const uint4* s1 = (const uint4*)w1T; uint4* d1 = (uint4*)sW1;
    for (int u = t; u < (96 * 20 * 2) / 16; u += 512) d1[u] = s1[u];
    const uint4* s2 = (const uint4*)w2T; uint4* d2 = (uint4*)sW2;
    for (int u = t; u < (160 * 116 * 2) / 16; u += 512) d2[u] = s2[u];
    for (int u = t; u < 960; u += 512) sAgg[u] = 0.f;
  }
  __syncthreads();

  const int rowg = R0 + w * 32;       // wave's first global row
  const int myrow = rowg + lm;

  // A0 fragment in registers: k0..6 = [xi, xj, dist], k7 = 1.0 (bias slot),
  // k8..15 = 0 (h==1 lanes all-zero; w1T zeros there too).
  short8v a0 = {0, 0, 0, 0, 0, 0, 0, 0};
  if (h == 0 && myrow < EDGE_ROWS) {
    int b = myrow / 5625, rb = myrow % 5625;
    int i = rb / 75, jj = rb % 75;
    const float* xb = x + b * 225;
    float xi0 = xb[i * 3], xi1 = xb[i * 3 + 1], xi2 = xb[i * 3 + 2];
    float xj0 = xb[jj * 3], xj1 = xb[jj * 3 + 1], xj2 = xb[jj * 3 + 2];
    float d0 = xj0 - xi0 + 1e-12f, d1 = xj1 - xi1 + 1e-12f, d2 = xj2 - xi2 + 1e-12f;
    float dist = sqrtf(d0 * d0 + d1 * d1 + d2 * d2);
    a0[0] = (short)f2bf(xi0); a0[1] = (short)f2bf(xi1); a0[2] = (short)f2bf(xi2);
    a0[3] = (short)f2bf(xj0); a0[4] = (short)f2bf(xj1); a0[5] = (short)f2bf(xj2);
    a0[6] = (short)f2bf(dist); a0[7] = (short)0x3F80;  // 1.0
  }

  // ---- L1 -> L2 accumulate; bias folded (L1 k=7, L2 k=96) ----
  float16v acc2[5];
#pragma unroll
  for (int n2 = 0; n2 < 5; ++n2) acc2[n2] = zero16();

#pragma unroll
  for (int nt1 = 0; nt1 < 3; ++nt1) {
    short8v wf = load8(sW1 + (nt1 * 32 + lm) * 20 + h * 8);
    float16v a = __builtin_amdgcn_mfma_f32_32x32x16_bf16(wf, a0, zero16(), 0, 0, 0);
    // lane (lm,h) holds H1[lm][nt1*32 + (r&3)+8(r>>2)+4h]; pack to 8 words
    uint32_t wp[8];
#pragma unroll
    for (int q = 0; q < 8; ++q)
      wp[q] = pk2(lrelu(a[2 * q]), lrelu(a[2 * q + 1]));
    // fragment for kt=nt1*2+kl via 2 permlane32_swaps
#pragma unroll
    for (int kl = 0; kl < 2; ++kl) {
      uint32_t s1a = wp[4 * kl + 0], s1b = wp[4 * kl + 2];
      uint32_t s2a = wp[4 * kl + 1], s2b = wp[4 * kl + 3];
      plswap(s1a, s1b);
      plswap(s2a, s2b);
      short8v hf = mk8(s1a, s2a, s1b, s2b);
      int kt = nt1 * 2 + kl;
#pragma unroll
      for (int n2 = 0; n2 < 5; ++n2) {
        short8v w2f = load8(sW2 + (n2 * 32 + lm) * 116 + kt * 16 + h * 8);
        acc2[n2] = __builtin_amdgcn_mfma_f32_32x32x16_bf16(w2f, hf, acc2[n2], 0, 0, 0);
      }
    }
  }
  {  // L2 bias K-step (k=96..111): B = const (1.0 at k=96 for h==0)
    short8v hc = {0, 0, 0, 0, 0, 0, 0, 0};
    if (h == 0) hc[0] = (short)0x3F80;
#pragma unroll
    for (int n2 = 0; n2 < 5; ++n2) {
      short8v w2f = load8(sW2 + (n2 * 32 + lm) * 116 + 96 + h * 8);
      acc2[n2] = __builtin_amdgcn_mfma_f32_32x32x16_bf16(w2f, hc, acc2[n2], 0, 0, 0);
    }
  }

  // ---- L2 finalize (in-register repack) -> L3 accumulate (W3 from L2) ----
  float16v acc3[6];
#pragma unroll
  for (int n3 = 0; n3 < 6; ++n3) acc3[n3] = zero16();

  const uint4* w3f4 = (const uint4*)w3G;
#pragma unroll
  for (int n2 = 0; n2 < 5; ++n2) {
    uint32_t wp[8];
#pragma unroll
    for (int q = 0; q < 8; ++q)
      wp[q] = pk2(lrelu(acc2[n2][2 * q]), lrelu(acc2[n2][2 * q + 1]));
#pragma unroll
    for (int kl = 0; kl < 2; ++kl) {
      uint32_t s1a = wp[4 * kl + 0], s1b = wp[4 * kl + 2];
      uint32_t s2a = wp[4 * kl + 1], s2b = wp[4 * kl + 3];
      plswap(s1a, s1b);
      plswap(s2a, s2b);
      short8v af = mk8(s1a, s2a, s1b, s2b);  // A = H2 rows, same k-mapping
#pragma unroll
      for (int n3 = 0; n3 < 6; ++n3) {
        union { uint4 u; short8v v; } wv;
        wv.u = w3f4[(n3 * 10 + n2 * 2 + kl) * 64 + l];  // coalesced 1KB fragment
        acc3[n3] = __builtin_amdgcn_mfma_f32_32x32x16_bf16(af, wv.v, acc3[n3], 0, 0, 0);
      }
    }
  }

  // ---- L3 finalize: bias + lrelu + masked j-sum into <=2 (b,i) groups ----
  {
    const int g0 = rowg / 75;
    const int gl0 = g0 - R0 / 75;            // 0..4
    const int s = 75 - rowg % 75;            // moff < s -> group g0
    const int vlim = min(32, EDGE_ROWS - rowg);
#pragma unroll
    for (int n3 = 0; n3 < 6; ++n3) {
      int col = n3 * 32 + lm;
      float bias = feb3[col];
      float p0 = 0.f, p1 = 0.f;
#pragma unroll
      for (int r = 0; r < 16; ++r) {
        int moff = (r & 3) + ((r >> 2) << 3) + (h << 2);
        float v = lrelu(acc3[n3][r] + bias);
        float vv = (moff < vlim) ? v : 0.f;
        if (moff < s) p0 += vv; else p1 += vv;
      }
      if (vlim > 0) {
        atomicAdd(&sAgg[gl0 * 192 + col], p0);
        if (s < 32) atomicAdd(&sAgg[(gl0 + 1) * 192 + col], p1);
      }
    }
  }

  __syncthreads();
  {  // flush block-local group sums to global (boundary groups shared -> atomic)
    const int gbase = R0 / 75;
    for (int u = t; u < 960; u += 512) {
      int g = gbase + u / 192;
      float v = sAgg[u];
      if (g < 9600 && v != 0.f) atomicAdd(&agg[g * 192 + (u % 192)], v);
    }
  }
}

// ---------------- node MLP (unchanged) ----------------
__global__ __launch_bounds__(512, 1)
void node_kernel(const float* __restrict__ x, const float* __restrict__ agg,
                 const float* __restrict__ fnb1, const float* __restrict__ fnb2,
                 const float* __restrict__ fnb3,
                 const uint16_t* __restrict__ fw1T, const uint16_t* __restrict__ fw2T,
                 const uint16_t* __restrict__ fw3T, float* __restrict__ out) {
  __shared__ __align__(16) uint16_t sY[64 * 228];
  __shared__ __align__(16) uint16_t sH1[64 * 260];
  __shared__ __align__(16) uint16_t sH2[64 * 260];
  __shared__ __align__(16) uint16_t sW[128 * 228];

  const int t = threadIdx.x;
  const int w = t >> 6, l = t & 63;
  const int n0 = blockIdx.x * 64;

  for (int u = t; u < 64 * 228; u += 512) {  // y hi/lo split
    int m = u / 228, c = u % 228;
    float v;
    if (c < 192) v = agg[(n0 + m) * 192 + c];
    else if (c < 195) v = x[(n0 + m) * 3 + (c - 192)];
    else v = 0.f;
    uint16_t hh = f2bf(v);
    sY[u] = hh;
    sH2[m * 260 + c] = f2bf(v - bf2f(hh));
  }
  __syncthreads();

  for (int p = 0; p < 2; ++p) {  // L1: hi+lo double MFMA
    const uint4* s = (const uint4*)(fw1T + p * 128 * 228);
    uint4* d = (uint4*)sW;
    for (int u = t; u < (128 * 228 * 2) / 16; u += 512) d[u] = s[u];
    __syncthreads();
    {
      int mt = w & 1, ntl = w >> 1;
      float16v acc = zero16();
      for (int kt = 0; kt < 14; ++kt) {
        short8v bb = frag32(sW, 228, ntl * 32, kt * 16, l);
        short8v ah = frag32(sY, 228, mt * 32, kt * 16, l);
        acc = __builtin_amdgcn_mfma_f32_32x32x16_bf16(ah, bb, acc, 0, 0, 0);
        short8v al = frag32(sH2, 260, mt * 32, kt * 16, l);
        acc = __builtin_amdgcn_mfma_f32_32x32x16_bf16(al, bb, acc, 0, 0, 0);
      }
      int col = (p * 4 + ntl) * 32 + (l & 31);
      float bias = fnb1[col];
#pragma unroll
      for (int r = 0; r < 16; ++r) {
        int row = (r & 3) + ((r >> 2) << 3) + ((l >> 5) << 2);
        sH1[(mt * 32 + row) * 260 + col] = f2bf(lrelu(acc[r] + bias));
      }
    }
    __syncthreads();
  }
  for (int q = 0; q < 4; ++q) {  // L2
    const uint4* s = (const uint4*)(fw2T + q * 64 * 260);
    uint4* d = (uint4*)sW;
    for (int u = t; u < (64 * 260 * 2) / 16; u += 512) d[u] = s[u];
    __syncthreads();
    if (w < 4) {
      int mt = w & 1, ntl = w >> 1;
      float16v acc = zero16();
      for (int kt = 0; kt < 16; ++kt) {
        short8v a = frag32(sH1, 260, mt * 32, kt * 16, l);
        short8v bb = frag32(sW, 260, ntl * 32, kt * 16, l);
        acc = __builtin_amdgcn_mfma_f32_32x32x16_bf16(a, bb, acc, 0, 0, 0);
      }
      int col = (q * 2 + ntl) * 32 + (l & 31);
      float bias = fnb2[col];
#pragma unroll
      for (int r = 0; r < 16; ++r) {
        int row = (r & 3) + ((r >> 2) << 3) + ((l >> 5) << 2);
        sH2[(mt * 32 + row) * 260 + col] = f2bf(lrelu(acc[r] + bias));
      }
    }
    __syncthreads();
  }
  if (w < 4) {  // L3: 256->3 linear, 16x16x32
    int mt = w;
    float4v acc = zero4();
    for (int kt = 0; kt < 8; ++kt) {
      short8v a = load8(sH2 + (mt * 16 + (l & 15)) * 260 + kt * 32 + ((l >> 4) << 3));
      short8v bb = load8(fw3T + (l & 15) * 260 + kt * 32 + ((l >> 4) << 3));
      acc = __builtin_amdgcn_mfma_f32_16x16x32_bf16(a, bb, acc, 0, 0, 0);
    }
    int col = l & 15;
    if (col < 3) {
      float bias = fnb3[col];
#pragma unroll
      for (int r = 0; r < 4; ++r) {
        int row = ((l >> 4) << 2) + r;
        out[(n0 + mt * 16 + row) * 3 + col] = acc[r] + bias;
      }
    }
  }
}

extern "C" void kernel_launch(void* const* d_in, const int* in_sizes, int n_in,
                              void* d_out, int out_size, void* d_ws, size_t ws_size,
                              hipStream_t stream) {
  (void)in_sizes; (void)n_in; (void)out_size; (void)ws_size;
  const float* x    = (const float*)d_in[0];
  const float* few1 = (const float*)d_in[1];
  const float* feb1 = (const float*)d_in[2];
  const float* few2 = (const float*)d_in[3];
  const float* feb2 = (const float*)d_in[4];
  const float* few3 = (const float*)d_in[5];
  const float* feb3 = (const float*)d_in[6];
  const float* fnw1 = (const float*)d_in[7];
  const float* fnb1 = (const float*)d_in[8];
  const float* fnw2 = (const float*)d_in[9];
  const float* fnb2 = (const float*)d_in[10];
  const float* fnw3 = (const float*)d_in[11];
  const float* fnb3 = (const float*)d_in[12];
  float* out = (float*)d_out;

  float* agg = (float*)d_ws;
  uint16_t* wsb = (uint16_t*)((char*)d_ws + 9600 * 192 * 4);
  const uint16_t* w1T  = wsb;
  const uint16_t* w2T  = wsb + S0;
  const uint16_t* w3G  = wsb + S0 + S1;
  const uint16_t* fw1T = wsb + S0 + S1 + S2;
  const uint16_t* fw2T = wsb + S0 + S1 + S2 + S3;
  const uint16_t* fw3T = wsb + S0 + S1 + S2 + S3 + S4;

  hipMemsetAsync(agg, 0, 9600 * 192 * sizeof(float), stream);  // atomic accum target
  prep_kernel<<<(PREP_TOTAL + 255) / 256, 256, 0, stream>>>(
      few1, feb1, few2, feb2, few3, fnw1, fnw2, fnw3, wsb);
  edge_kernel<<<EDGE_BLOCKS, 512, 0, stream>>>(x, feb3, w1T, w2T, w3G, agg);
  node_kernel<<<150, 512, 0, stream>>>(x, agg, fnb1, fnb2, fnb3, fw1T, fw2T, fw3T, out);
}